// Round 11
// baseline (302.145 us; speedup 1.0000x reference)
//
#include <hip/hip_runtime.h>
#include <hip/hip_fp16.h>
#include <cmath>

#define D 64
#define KTOT 1024
#define MARGIN_P 0.03125f  // flag margin: pack-trunc (<=0.0156) + fp16-2term err (sigma~2e-3)
#define WLCAP 32768        // refine worklist capacity
#define PMASK 0x3FFFFu     // low 18 bits: point id (N = 2^18)
#define NB 128             // blocks for hist/place counting sort

typedef __attribute__((ext_vector_type(8))) _Float16 half8;  // 8 fp16 = 4 VGPRs (MFMA A/B frag)
typedef __attribute__((ext_vector_type(4))) float f32x4;     // MFMA C/D frag

// ---------------- K0: pack w (fp16 B-frag) + transpose + wn + zero-init (fused) ----------------
// blocks [0,256): pack + zero cs slice; blocks [256,260): wn[k] = 0.5*||w_k||^2 fp64
__global__ void k_prep(const float* __restrict__ w, unsigned short* __restrict__ wpack_hi,
                       float* __restrict__ wT, float* __restrict__ wn,
                       float* __restrict__ cs, int* __restrict__ wl_count, int K)
{
    const int nprep = (D * K) / 256;   // 256
    const int b = blockIdx.x;
    if (b < nprep) {
        int i = b * 256 + threadIdx.x;           // i = d*K + k
        int d = i / K, k = i % K;
        float f = w[i];
        _Float16 h = (_Float16)f;                // RNE
        int t = k >> 4, n = k & 15;
        int kc = d >> 5, q = (d >> 3) & 3, j = d & 7;
        size_t fi = ((size_t)((t * 2 + kc) * 64 + q * 16 + n)) * 8 + j;
        __half hh = *(__half*)&h;
        wpack_hi[fi] = __half_as_ushort(hh);
        wT[(size_t)k * D + d] = f;
        cs[i] = 0.f;                             // same DK range: fused zero-init
    } else {
        int k = (b - nprep) * 256 + threadIdx.x;
        if (b == nprep && threadIdx.x == 0) wl_count[0] = 0;
        if (k >= K) return;
        double s = 0.0;
        for (int d = 0; d < D; ++d) {
            double v = (double)w[(size_t)d * K + k];
            s += v * v;
        }
        wn[k] = (float)(0.5 * s);
    }
}

// ---------------- K2: MFMA assign (fp16 2-term, 64 pts/wave), packed argmax + worklist ----------------
__global__ __launch_bounds__(256, 2) void k_assign(
    const float* __restrict__ x, const unsigned short* __restrict__ wpack_hi,
    const float* __restrict__ wn, unsigned int* __restrict__ idx_out,
    int* __restrict__ wl, int* __restrict__ wl_count, int N, int K)
{
    __shared__ __align__(16) unsigned short lds_hi[8192];  // 16 KB
    __shared__ float lds_wn[128];
    __shared__ int l_wl[256];    // 256 = max points/block
    __shared__ int l_cnt, l_base;

    const int tid = threadIdx.x;
    const int wv = tid >> 6, lane = tid & 63;
    const int col = lane & 15, quad = lane >> 4;
    const long long n0 = (long long)blockIdx.x * 256 + wv * 64;
    if (tid == 0) l_cnt = 0;

    // A-frags: 4 m-tiles x 2 k-halves, x split into fp16 hi/lo
    half8 a_hi[4][2], a_lo[4][2];
    #pragma unroll
    for (int mt = 0; mt < 4; ++mt) {
        long long row = n0 + mt * 16 + col;
        if (row >= N) row = N - 1;
        const float* xr = x + row * D;
        #pragma unroll
        for (int kc = 0; kc < 2; ++kc) {
            const int dbase = kc * 32 + quad * 8;
            float4 f0 = *(const float4*)(xr + dbase);
            float4 f1 = *(const float4*)(xr + dbase + 4);
            float xs[8] = {f0.x, f0.y, f0.z, f0.w, f1.x, f1.y, f1.z, f1.w};
            half8 h, l;
            #pragma unroll
            for (int j = 0; j < 8; ++j) {
                _Float16 hj = (_Float16)xs[j];
                h[j] = hj;
                l[j] = (_Float16)(xs[j] - (float)hj);
            }
            a_hi[mt][kc] = h;
            a_lo[mt][kc] = l;
        }
    }

    // packed (biased-value | 1023-code): max_u32 argmax, min/max top-2
    unsigned best[16], sec[16];
    #pragma unroll
    for (int s = 0; s < 16; ++s) { best[s] = 0u; sec[s] = 0u; }

    const int nchunks = K / 128;
    for (int c = 0; c < nchunks; ++c) {
        __syncthreads();
        {   // stage 16 KB + 512 B wn
            const uint4* gh = (const uint4*)(wpack_hi + (size_t)c * 8192);
            uint4* lh = (uint4*)lds_hi;
            #pragma unroll
            for (int i = 0; i < 4; ++i)
                lh[tid + 256 * i] = gh[tid + 256 * i];
            if (tid < 128) lds_wn[tid] = wn[c * 128 + tid];
        }
        __syncthreads();

        #pragma unroll
        for (int tl = 0; tl < 8; ++tl) {
            const int fb = (tl * 2) * 512 + (quad * 16 + col) * 8;
            half8 bh0 = *(const half8*)(lds_hi + fb);
            half8 bh1 = *(const half8*)(lds_hi + fb + 512);
            const float base = 128.0f - lds_wn[tl * 16 + col];   // bias + (-wn) in acc init
            const unsigned codebits = 1023u - (unsigned)((c * 8 + tl) * 16 + col);
            #pragma unroll
            for (int mt = 0; mt < 4; ++mt) {
                f32x4 acc = {base, base, base, base};
                acc = __builtin_amdgcn_mfma_f32_16x16x32_f16(a_hi[mt][0], bh0, acc, 0, 0, 0);
                acc = __builtin_amdgcn_mfma_f32_16x16x32_f16(a_hi[mt][1], bh1, acc, 0, 0, 0);
                acc = __builtin_amdgcn_mfma_f32_16x16x32_f16(a_lo[mt][0], bh0, acc, 0, 0, 0);
                acc = __builtin_amdgcn_mfma_f32_16x16x32_f16(a_lo[mt][1], bh1, acc, 0, 0, 0);
                #pragma unroll
                for (int r = 0; r < 4; ++r) {
                    unsigned pv = (__float_as_uint(acc[r]) & 0xFFFFFC00u) | codebits;
                    int s = mt * 4 + r;
                    unsigned b = best[s];
                    unsigned mn = pv < b ? pv : b;
                    best[s] = pv > b ? pv : b;
                    sec[s]  = mn > sec[s] ? mn : sec[s];
                }
            }
        }
    }

    // top-2 merge across the 16 columns
    #pragma unroll
    for (int m = 1; m < 16; m <<= 1) {
        #pragma unroll
        for (int s = 0; s < 16; ++s) {
            unsigned ob = __shfl_xor(best[s], m);
            unsigned os = __shfl_xor(sec[s], m);
            unsigned mn = ob < best[s] ? ob : best[s];
            best[s] = ob > best[s] ? ob : best[s];
            sec[s]  = os > sec[s] ? os : sec[s];
            sec[s]  = mn > sec[s] ? mn : sec[s];
        }
    }

    if (col == 0) {
        #pragma unroll
        for (int s = 0; s < 16; ++s) {
            int mt = s >> 2, r = s & 3;
            long long np = n0 + mt * 16 + quad * 4 + r;   // C row = quad*4 + reg
            if (np < N) {
                unsigned code = 1023u - (best[s] & 0x3FFu);
                float vb = __uint_as_float(best[s] & 0xFFFFFC00u);
                float vs = __uint_as_float(sec[s] & 0xFFFFFC00u);
                if ((vb - vs) < MARGIN_P) {
                    idx_out[np] = code | 0x80000000u;
                    int q = atomicAdd(&l_cnt, 1);        // LDS atomic
                    l_wl[q] = (int)np;
                } else {
                    idx_out[np] = code;
                }
            }
        }
    }
    __syncthreads();
    if (tid == 0 && l_cnt > 0) l_base = atomicAdd(wl_count, l_cnt);  // 1 global RMW/block
    __syncthreads();
    for (int i = tid; i < l_cnt; i += 256) {
        int pos = l_base + i;
        if (pos < WLCAP) wl[pos] = l_wl[i];
    }
}

// ---------------- K3: fp64 exact rescan of worklist points ----------------
__global__ void k_refine(const float* __restrict__ x, const float* __restrict__ w,
                         unsigned int* __restrict__ idx_io, const int* __restrict__ wl,
                         const int* __restrict__ wl_count, int N, int K)
{
    const int gtid = blockIdx.x * blockDim.x + threadIdx.x;
    const int lane = threadIdx.x & 63;
    const int wave = gtid >> 6;
    const int nwaves = (gridDim.x * blockDim.x) >> 6;
    int nw = wl_count[0];
    if (nw > WLCAP) nw = WLCAP;

    for (int i = wave; i < nw; i += nwaves) {
        long long p = wl[i];
        const float* __restrict__ xp = x + p * D;   // wave-uniform broadcast, L1-hot
        double bt = -1e300;
        int bk = 0;
        for (int k = lane; k < K; k += 64) {        // ascending k/lane; strict > = first-occurrence
            double t = 0.0, s = 0.0;
            #pragma unroll 8
            for (int d = 0; d < D; ++d) {
                double wd = (double)w[(size_t)d * K + k];
                t = fma((double)xp[d], wd, t);
                s = fma(wd, wd, s);
            }
            t -= 0.5 * s;
            if (t > bt) { bt = t; bk = k; }
        }
        #pragma unroll
        for (int off = 32; off > 0; off >>= 1) {
            double ot = __shfl_down(bt, off);
            int    ok = __shfl_down(bk, off);
            if (ot > bt || (ot == bt && ok < bk)) { bt = ot; bk = ok; }
        }
        int fk = __shfl(bk, 0);
        if (lane == 0) idx_io[p] = (unsigned)fk;    // clear flag
    }
}

// ---------------- K4: per-block histogram, plain writes (no global atomics) ----------------
__global__ void k_hist2(const unsigned int* __restrict__ idx, int* __restrict__ hist, int N)
{
    __shared__ int h[KTOT];
    const int tid = threadIdx.x;
    const int b = blockIdx.x;
    for (int i = tid; i < KTOT; i += blockDim.x) h[i] = 0;
    __syncthreads();
    const int chunk = N / NB;
    const int p0 = b * chunk;
    for (int i = tid; i < chunk; i += blockDim.x)
        atomicAdd(&h[idx[p0 + i] & 0x7fffffffu], 1);
    __syncthreads();
    for (int i = tid; i < KTOT; i += blockDim.x)
        hist[(size_t)b * KTOT + i] = h[i];
}

// ---------------- K5: fused per-code block-scan + code prefix-scan (1 block, 1024 thr) ----------------
__global__ void k_totscan(int* __restrict__ hist, int* __restrict__ counts,
                          int* __restrict__ offsets)
{
    __shared__ int a[KTOT];
    const int k = threadIdx.x;
    int run = 0;
    #pragma unroll 8
    for (int b = 0; b < NB; ++b) {               // coalesced across k
        int t = hist[(size_t)b * KTOT + k];
        hist[(size_t)b * KTOT + k] = run;
        run += t;
    }
    counts[k] = run;
    a[k] = run;
    __syncthreads();
    for (int off = 1; off < KTOT; off <<= 1) {
        int v = (k >= off) ? a[k - off] : 0;
        __syncthreads();
        a[k] += v;
        __syncthreads();
    }
    offsets[k] = a[k] - run;
}

// ---------------- K6: place via LDS cursors (zero global atomics) ----------------
__global__ void k_place2(const unsigned int* __restrict__ idx, const int* __restrict__ hist,
                         const int* __restrict__ offsets, unsigned* __restrict__ order, int N)
{
    __shared__ int cur[KTOT];
    const int tid = threadIdx.x;
    const int b = blockIdx.x;
    for (int i = tid; i < KTOT; i += blockDim.x)
        cur[i] = offsets[i] + hist[(size_t)b * KTOT + i];
    __syncthreads();
    const int chunk = N / NB;
    const int p0 = b * chunk;
    for (int i = tid; i < chunk; i += blockDim.x) {
        int p = p0 + i;
        unsigned k = idx[p] & 0x7fffffffu;
        int pos = atomicAdd(&cur[k], 1);         // LDS atomic; worst code ~60 RMWs/block
        order[pos] = (k << 18) | (unsigned)p;
    }
}

// ---------------- K7: run-length segment sum + quant gather, 4-deep prefetch ring ----------------
// R10 suspicion: 1-deep pipeline = 1 outstanding 256B gather/wave, latency-bound.
// 4-deep ring gives 4 outstanding loads -> ~4x gather throughput.
__global__ void k_sum(const float* __restrict__ x, const float* __restrict__ wT,
                      const unsigned* __restrict__ order, float* __restrict__ quant,
                      float* __restrict__ cs, int N)
{
    const int gtid = blockIdx.x * blockDim.x + threadIdx.x;
    const int lane = threadIdx.x & 63;
    const int wave = gtid >> 6;
    const int nwaves = (gridDim.x * blockDim.x) >> 6;
    const int nchunks = (N + 63) >> 6;

    for (int c = wave; c < nchunks; c += nwaves) {
        const int base = c << 6;
        const int cnt = min(64, N - base);
        unsigned e = order[base + min(lane, cnt - 1)];   // coalesced 256B

        float v[4];
        int kk[4], pp[4];
        #pragma unroll
        for (int j = 0; j < 4; ++j) {
            unsigned ej = __shfl(e, min(j, cnt - 1));
            kk[j] = (int)(ej >> 18);
            pp[j] = (int)(ej & PMASK);
            v[j] = x[(size_t)pp[j] * D + lane];
        }
        int curk = -1;
        float acc = 0.f, wrow = 0.f;
        #pragma unroll 4
        for (int i = 0; i < cnt; ++i) {
            const int sl = i & 3;
            const int ki = kk[sl], pi = pp[sl];
            const float vi = v[sl];
            const int nj = i + 4;
            if (nj < cnt) {                              // wave-uniform
                unsigned en = __shfl(e, nj);
                kk[sl] = (int)(en >> 18);
                pp[sl] = (int)(en & PMASK);
                v[sl] = x[(size_t)pp[sl] * D + lane];
            }
            if (ki != curk) {                            // wave-uniform
                if (curk >= 0) unsafeAtomicAdd(&cs[(size_t)curk * D + lane], acc);
                wrow = wT[(size_t)ki * D + lane];        // L2-hot
                acc = vi;
                curk = ki;
            } else {
                acc += vi;
            }
            quant[(size_t)pi * D + lane] = wrow;
        }
        unsafeAtomicAdd(&cs[(size_t)curk * D + lane], acc);
    }
}

// ---------------- K8: EMA combine -> new_w [D][K] ----------------
__global__ void k_combine(const float* __restrict__ c_sum, const float* __restrict__ c_n,
                          const float* __restrict__ cs, const int* __restrict__ counts,
                          float* __restrict__ outw, int K)
{
    int i = blockIdx.x * blockDim.x + threadIdx.x;   // i = d*K + k
    if (i >= D * K) return;
    int k = i % K;
    int d = i / K;
    const float g  = 0.99f;
    const float og = (float)(1.0 - 0.99);
    float ns = c_sum[i] * g + cs[(size_t)k * D + d] * og;
    float nn = c_n[k] * g + (float)counts[k] * og;
    outw[i] = ns / nn;
}

extern "C" void kernel_launch(void* const* d_in, const int* in_sizes, int n_in,
                              void* d_out, int out_size, void* d_ws, size_t ws_size,
                              hipStream_t stream)
{
    const float* x     = (const float*)d_in[0];
    const float* w     = (const float*)d_in[1];
    const float* c_sum = (const float*)d_in[2];
    const float* c_n   = (const float*)d_in[3];
    const int N = in_sizes[0] / D;
    const int K = in_sizes[3];

    float* quant = (float*)d_out;                      // N*D
    float* outw  = (float*)d_out + (size_t)N * D;      // D*K

    // ws layout: [cs K*D][wl_count 1][hist NB*K][counts K][offsets K]
    //            [wl WLCAP][order N][idx N][wn K][wT K*D][wpack_hi K*D ushort]
    char* ws = (char*)d_ws;
    float* cs       = (float*)ws;                      // K*D (zeroed by k_prep)
    int* wl_count   = (int*)(cs + (size_t)K * D);      // 1  (zeroed by k_prep)
    int* hist       = wl_count + 1;                    // NB*K (fully written by k_hist2)
    int* counts     = hist + (size_t)NB * KTOT;        // K
    int* offsets    = counts + K;                      // K
    int* wl         = offsets + K;                     // WLCAP
    unsigned* order = (unsigned*)(wl + WLCAP);         // N
    unsigned* idx   = order + N;                       // N
    float* wn       = (float*)(idx + N);               // K
    float* wT       = wn + K;                          // K*D
    unsigned short* wpack_hi = (unsigned short*)(wT + (size_t)K * D);

    k_prep<<<(D * K) / 256 + 4, 256, 0, stream>>>(w, wpack_hi, wT, wn, cs, wl_count, K);

    k_assign<<<(N + 255) / 256, 256, 0, stream>>>(x, wpack_hi, wn, idx, wl, wl_count, N, K);
    k_refine<<<1024, 256, 0, stream>>>(x, w, idx, wl, wl_count, N, K);

    k_hist2<<<NB, 256, 0, stream>>>(idx, hist, N);
    k_totscan<<<1, KTOT, 0, stream>>>(hist, counts, offsets);
    k_place2<<<NB, 256, 0, stream>>>(idx, hist, offsets, order, N);
    k_sum<<<1024, 256, 0, stream>>>(x, wT, order, quant, cs, N);
    k_combine<<<(D * K + 255) / 256, 256, 0, stream>>>(c_sum, c_n, cs, counts, outw, K);
}